// Round 2
// baseline (60.078 us; speedup 1.0000x reference)
//
#include <hip/hip_runtime.h>
#include <math.h>

// TransferMatrixMethod: B=256 batches, L=64 layers (62 inner), W=512 wavelengths.
// M_layer = [[cos p, -i sin p / n],[-i n sin p, cos p]] -- real diagonal,
// pure-imaginary off-diagonal. Closed under product: carry as 4 reals
// M = [[A, i*Bi],[i*Ci, D]].
//   X@Y: A' = Ax*Ay - Bx*Cy; B' = Ax*By + Bx*Dy; C' = Cx*Ay + Dx*Cy; D' = Dx*Dy - Cx*By
// Final: E = A+1e-9 + i*Bi*n_sub ; H = D*n_sub + i*Ci
//   r = (n_in*E - H)/(n_in*E + H);  R = |num|^2/|den|^2   (division cleared)
//
// R4 == R3 resubmit (R3 bench was an infra failure: "container failed twice").
// R3 changes vs R2 (R2 = 59.9 us total; tmm_kernel itself ~20 us, latency-bound
// at 2 waves/SIMD with a 62-step serial FMA chain):
//  - ASSOCIATIVE CHAIN SPLIT: the 62-layer product is split into 4 chunks
//    (16/16/16/14), one per wave. Each block now covers 64 wavelengths with
//    4 waves, grid = 2048 blocks -> 8192 waves = 8 waves/SIMD (was 2),
//    and the serial dependency chain per wave is 16 steps (was 62).
//  - Chunk partials (4 reals each) staged in LDS [4][64] (stride-1, conflict
//    free); wave 0 does the 3-product tree combine + Fresnel + store.
//  - Per-layer math unchanged: rev-domain v_sin/v_cos, hoisted 1/n, no divide.

#define TMM_B 256
#define TMM_L 64
#define TMM_W 512

__global__ __launch_bounds__(256) void tmm_kernel(
    const float* __restrict__ n_layers,   // [B][L]
    const float* __restrict__ d_layers,   // [B][L]
    const float* __restrict__ wavelengths,// [W]
    float* __restrict__ out)              // [B][W]
{
    __shared__ float s_n[TMM_L];
    __shared__ float s_nd[TMM_L];
    __shared__ float s_invn[TMM_L];
    __shared__ float s_pA[4][64];
    __shared__ float s_pB[4][64];
    __shared__ float s_pC[4][64];
    __shared__ float s_pD[4][64];

    const int b    = blockIdx.x >> 3;        // 8 wavelength-groups per batch row
    const int wgrp = blockIdx.x & 7;         // which group of 64 wavelengths
    const int tid  = threadIdx.x;
    const int wl   = tid & 63;               // wavelength within group
    const int g    = tid >> 6;               // chunk id == wave id (0..3)

    if (tid < TMM_L) {
        const float n = n_layers[b * TMM_L + tid];
        const float d = d_layers[b * TMM_L + tid];
        s_n[tid]    = n;
        s_nd[tid]   = n * d;
        s_invn[tid] = __frcp_rn(n + 1e-8f);  // hoisted out of the layer loop
    }
    __syncthreads();

    const int w       = (wgrp << 6) | wl;
    const float ilam  = __frcp_rn(wavelengths[w]);  // phi in revolutions = n*d/lam

    float A = 1.0f, Bi = 0.0f, Ci = 0.0f, D = 1.0f;

#define TMM_STEP(l) do {                                            \
        const float n_   = s_n[(l)];   /* LDS broadcast */          \
        const float rev  = s_nd[(l)] * ilam;                        \
        const float sp   = __builtin_amdgcn_sinf(rev); /* v_sin */  \
        const float cp   = __builtin_amdgcn_cosf(rev); /* v_cos */  \
        const float bco  = -sp * s_invn[(l)];                       \
        const float cco  = -n_ * sp;                                \
        const float A2 = A  * cp  - Bi * cco;                       \
        const float B2 = A  * bco + Bi * cp;                        \
        const float C2 = Ci * cp  + D  * cco;                       \
        const float D2 = D  * cp  - Ci * bco;                       \
        A = A2; Bi = B2; Ci = C2; D = D2;                           \
    } while (0)

    // Inner layers l = 1..62 split as chunks 1-16 / 17-32 / 33-48 / 49-62.
    // Branch is wave-uniform (g is constant per wave) -> no lane divergence.
    if (g == 3) {
        #pragma unroll
        for (int i = 0; i < 14; ++i) TMM_STEP(49 + i);
    } else {
        const int base = 1 + g * 16;
        #pragma unroll
        for (int i = 0; i < 16; ++i) TMM_STEP(base + i);
    }
#undef TMM_STEP

    // Stage chunk partial products (stride-1 within wave: conflict-free).
    s_pA[g][wl] = A;
    s_pB[g][wl] = Bi;
    s_pC[g][wl] = Ci;
    s_pD[g][wl] = D;
    __syncthreads();

    // Tree combine + Fresnel on wave 0 only (~40 VALU ops, negligible).
    if (tid < 64) {
        const float a0 = s_pA[0][wl], b0 = s_pB[0][wl], c0 = s_pC[0][wl], d0 = s_pD[0][wl];
        const float a1 = s_pA[1][wl], b1 = s_pB[1][wl], c1 = s_pC[1][wl], d1 = s_pD[1][wl];
        const float a2 = s_pA[2][wl], b2 = s_pB[2][wl], c2 = s_pC[2][wl], d2 = s_pD[2][wl];
        const float a3 = s_pA[3][wl], b3 = s_pB[3][wl], c3 = s_pC[3][wl], d3 = s_pD[3][wl];

        // Q0 = P0 @ P1
        const float qa = a0*a1 - b0*c1;
        const float qb = a0*b1 + b0*d1;
        const float qc = c0*a1 + d0*c1;
        const float qd = d0*d1 - c0*b1;
        // Q1 = P2 @ P3
        const float ra = a2*a3 - b2*c3;
        const float rb = a2*b3 + b2*d3;
        const float rc = c2*a3 + d2*c3;
        const float rd = d2*d3 - c2*b3;
        // M = Q0 @ Q1
        const float MA = qa*ra - qb*rc;
        const float MB = qa*rb + qb*rd;
        const float MC = qc*ra + qd*rc;
        const float MD = qd*rd - qc*rb;

        const float n_in  = s_n[0];
        const float n_sub = s_n[TMM_L - 1];

        const float E_re = MA + 1e-9f;      // E_in + 1e-9 (real part)
        const float E_im = MB * n_sub;
        const float H_re = MD * n_sub;
        const float H_im = MC;

        const float num_re = n_in * E_re - H_re;
        const float num_im = n_in * E_im - H_im;
        const float den_re = n_in * E_re + H_re;
        const float den_im = n_in * E_im + H_im;

        const float R = (num_re * num_re + num_im * num_im) /
                        (den_re * den_re + den_im * den_im);

        out[b * TMM_W + w] = R;
    }
}

extern "C" void kernel_launch(void* const* d_in, const int* in_sizes, int n_in,
                              void* d_out, int out_size, void* d_ws, size_t ws_size,
                              hipStream_t stream) {
    const float* n_layers    = (const float*)d_in[0];   // 256*64
    const float* d_layers    = (const float*)d_in[1];   // 256*64
    const float* wavelengths = (const float*)d_in[2];   // 512
    float* out = (float*)d_out;                         // 256*512

    dim3 grid(TMM_B * 8);   // 2048 blocks: (batch, 64-wavelength group)
    dim3 block(256);        // 4 waves = 4 chain chunks
    tmm_kernel<<<grid, block, 0, stream>>>(n_layers, d_layers, wavelengths, out);
}